// Round 10
// baseline (469.179 us; speedup 1.0000x reference)
//
#include <hip/hip_runtime.h>
#include <hip/hip_bf16.h>
#include <stdint.h>

// B=4, S=2048, D=1024, H=16, hd=64.
// Inputs fp32 or bf16 (wave-ballot probe in cvt kernels only); downstream is
// pure bf16. OUTPUT IS FLOAT32.
//
// Buffer plan (64MB ws + d_out-as-scratch):
//   ws:    qk 32MB | vt 16MB | attnbuf 16MB
//   xb  (16MB bf16) -> attnbuf region  (dead before attn writes it)
//   wqb ( 6MB bf16) -> d_out scratch   (read by gemm1 only; gemm1 writes ws)
//   wob ( 2MB bf16) -> vtbuf region    (converted after attn; vt dead then)

typedef __bf16 bf16_t;
typedef __attribute__((ext_vector_type(8))) __bf16 bf16x8;
typedef __attribute__((ext_vector_type(4))) __bf16 bf16x4;
typedef __attribute__((ext_vector_type(4))) float f32x4;

#define LOG2E 1.44269504088896340736f
#define SCLF (0.125f * LOG2E)
#define MFMA16(a, b, c) __builtin_amdgcn_mfma_f32_16x16x32_bf16(a, b, c, 0, 0, 0)

__device__ __forceinline__ bf16x8 ld8(const bf16_t* p) {
    return *(const bf16x8*)p;
}
__device__ __forceinline__ bf16x8 cvt8(const float* p) {
    f32x4 a = *(const f32x4*)p;
    f32x4 b = *(const f32x4*)(p + 4);
    bf16x8 r;
    r[0] = (bf16_t)a[0]; r[1] = (bf16_t)a[1]; r[2] = (bf16_t)a[2]; r[3] = (bf16_t)a[3];
    r[4] = (bf16_t)b[0]; r[5] = (bf16_t)b[1]; r[6] = (bf16_t)b[2]; r[7] = (bf16_t)b[3];
    return r;
}

// Zero-cost liveness pin: forces the 4 sub-loads of a fragment to be issued
// together and co-resident at this point (MLP=4, single waitcnt). Defeats
// the allocator's 32-VGPR tier collapse that serialized loads in R8
// (VGPR=32, 255us) and the scratch spill of R7.
__device__ __forceinline__ void keep(const bf16x8& v) {
    asm volatile("" :: "v"(v));
}

// dtype probe, wave-cooperative: ONE coalesced load per lane + ballot.
__device__ __forceinline__ bool probe_f32_wave(const void* w) {
    const uint16_t* u = (const uint16_t*)w;
    const int lane = threadIdx.x & 63;
    const int e = (u[lane] >> 7) & 0xFF;
    const unsigned long long m = __ballot(e >= 96 && e <= 150);
    return __popcll(m) < 56;
}

// async global->LDS, 16B per lane. LDS dest: wave-uniform base + lane*16.
__device__ __forceinline__ void gll16(const bf16_t* g, bf16_t* l) {
    __builtin_amdgcn_global_load_lds(
        (const __attribute__((address_space(1))) void*)g,
        (__attribute__((address_space(3))) void*)l, 16, 0, 0);
}

// ---------------------------------------------------------------------------
// Input conversion (fp32->bf16, or bf16 copy), 8 elems/thread.
// ---------------------------------------------------------------------------
__global__ __launch_bounds__(256) void cvt_big_kernel(
    const void* __restrict__ x, const void* __restrict__ wq,
    bf16_t* __restrict__ xb, bf16_t* __restrict__ wqb)
{
    const int gid = blockIdx.x * 256 + threadIdx.x;
    const void* src;
    bf16_t* dst;
    int off;
    if (gid < 1048576) { src = x;  dst = xb;  off = gid; }
    else               { src = wq; dst = wqb; off = gid - 1048576; }
    const bool f32 = probe_f32_wave(src);
    const bf16x8 v = f32 ? cvt8((const float*)src + (size_t)off * 8)
                         : ld8((const bf16_t*)src + (size_t)off * 8);
    *(bf16x8*)(dst + (size_t)off * 8) = v;
}

__global__ __launch_bounds__(256) void cvt_small_kernel(
    const void* __restrict__ wo, bf16_t* __restrict__ wob)
{
    const int off = blockIdx.x * 256 + threadIdx.x;
    const bool f32 = probe_f32_wave(wo);
    const bf16x8 v = f32 ? cvt8((const float*)wo + (size_t)off * 8)
                         : ld8((const bf16_t*)wo + (size_t)off * 8);
    *(bf16x8*)(wob + (size_t)off * 8) = v;
}

// ---------------------------------------------------------------------------
// GEMM (pure bf16): C = A[M,K] @ B[N,K]^T, 128x128 tile, BK=32,
// global_load_lds width-16 staging (m97 structure) + bijective XCD swizzle
// (nwg % 8 == 0 for both calls: 1536, 512) for L2 panel locality.
// EPI==0: C float*, plain [M,N]. EPI==1: C bf16* Q|K split + VT scatter.
// ---------------------------------------------------------------------------
template <int EPI>
__global__ __launch_bounds__(256) void gemm_bt_lds(
    const bf16_t* __restrict__ A, const bf16_t* __restrict__ B,
    void* __restrict__ C, bf16_t* __restrict__ VT,
    int M, int N, int K)
{
    __shared__ __align__(16) bf16_t lsA[128 * 32];
    __shared__ __align__(16) bf16_t lsB[128 * 32];

    const int t    = threadIdx.x;
    const int lane = t & 63;
    const int wid  = t >> 6;
    const int quad = lane >> 4;
    const int l15  = lane & 15;
    const int wm   = (wid & 1) * 64;
    const int wn   = (wid >> 1) * 64;

    // XCD-aware bijective swizzle: hw dispatch round-robins bid%8 across
    // XCDs; remap so each XCD owns a CONTIGUOUS run of tiles (shared panels).
    const int nbx = gridDim.x;
    const int nwg = nbx * gridDim.y;
    const int bid = blockIdx.y * nbx + blockIdx.x;
    const int sid = (bid & 7) * (nwg >> 3) + (bid >> 3);
    const int m0  = (sid / nbx) * 128;
    const int n0  = (sid % nbx) * 128;

    // thread t stages 16B: row (t>>2), col (t&3)*8 -> LDS byte t*16 (linear)
    const bf16_t* Ar = A + (size_t)(m0 + (t >> 2)) * K + (t & 3) * 8;
    const bf16_t* Br = B + (size_t)(n0 + (t >> 2)) * K + (t & 3) * 8;
    bf16_t* la = lsA + t * 8;
    bf16_t* lb = lsB + t * 8;

    f32x4 acc[4][4];
#pragma unroll
    for (int i = 0; i < 4; ++i)
#pragma unroll
        for (int j = 0; j < 4; ++j) acc[i][j] = (f32x4){0.f, 0.f, 0.f, 0.f};

    for (int k0 = 0; k0 < K; k0 += 32) {
        __syncthreads();   // previous tile's readers done
        gll16(Ar + k0, la);
        gll16(Ar + (size_t)64 * K + k0, la + 2048);
        gll16(Br + k0, lb);
        gll16(Br + (size_t)64 * K + k0, lb + 2048);
        __syncthreads();   // compiler drains vmcnt before s_barrier

        bf16x8 af[4], bfr[4];
#pragma unroll
        for (int i = 0; i < 4; ++i)
            af[i] = ld8(lsA + (wm + i * 16 + l15) * 32 + quad * 8);
#pragma unroll
        for (int j = 0; j < 4; ++j)
            bfr[j] = ld8(lsB + (wn + j * 16 + l15) * 32 + quad * 8);
#pragma unroll
        for (int i = 0; i < 4; ++i)
#pragma unroll
            for (int j = 0; j < 4; ++j)
                acc[i][j] = MFMA16(af[i], bfr[j], acc[i][j]);
    }

#pragma unroll
    for (int i = 0; i < 4; ++i) {
        const int row = m0 + wm + i * 16 + quad * 4;
#pragma unroll
        for (int j = 0; j < 4; ++j) {
            const int col = n0 + wn + j * 16 + l15;
#pragma unroll
            for (int r = 0; r < 4; ++r) {
                const int rr = row + r;
                if (EPI == 0) {
                    ((float*)C)[(size_t)rr * N + col] = acc[i][j][r];
                } else {
                    const bf16_t v = (bf16_t)acc[i][j][r];
                    if (col < 2048) {
                        ((bf16_t*)C)[(size_t)rr * 2048 + col] = v;
                    } else {
                        const int c2 = col - 2048;
                        const int h = c2 >> 6, d = c2 & 63;
                        const int b = rr >> 11, s = rr & 2047;
                        VT[((size_t)((b << 4) + h) * 64 + d) * 2048 + s] = v;
                    }
                }
            }
        }
    }
}

// ---------------------------------------------------------------------------
// Flash attention (causal), NO-RESCALE, QBLK=16/wave.
// R8 schedule (8192 wave-tasks, 2048 blocks, per-SIMD-balanced, XCD-affine)
// + keep() liveness pins after each fragment load. R8's 255us regression was
// the allocator choosing the 32-VGPR tier and serializing the 16B loads
// (MLP=1, full L2 latency each); the pins force whole-fragment residency
// (MLP=4). Target: VGPR <= 64 -> 8 resident waves/SIMD.
// ---------------------------------------------------------------------------
struct Kfrag { bf16x8 k00, k01, k10, k11; };
struct Vfrag { bf16x8 v0, v1, v2, v3; };

__device__ __forceinline__ Kfrag ldk(const bf16_t* Kbase, int key0) {
    const bf16_t* kp = Kbase + (size_t)key0 * 2048;
    Kfrag f;
    f.k00 = ld8(kp);
    f.k01 = ld8(kp + 32);
    f.k10 = ld8(kp + (size_t)16 * 2048);
    f.k11 = ld8(kp + (size_t)16 * 2048 + 32);
    return f;
}
__device__ __forceinline__ Vfrag ldv(const bf16_t* Vbase, int key0) {
    const bf16_t* vp = Vbase + key0;
    Vfrag f;
    f.v0 = ld8(vp);
    f.v1 = ld8(vp + (size_t)16 * 2048);
    f.v2 = ld8(vp + (size_t)32 * 2048);
    f.v3 = ld8(vp + (size_t)48 * 2048);
    return f;
}

__device__ __forceinline__ bf16x4 expq(f32x4 s, float& lsum) {
    bf16x4 r;
#pragma unroll
    for (int i = 0; i < 4; ++i) {
        const float e = exp2f(s[i] * SCLF);
        r[i] = (bf16_t)e;
        lsum += (float)r[i];
    }
    return r;
}
__device__ __forceinline__ bf16x4 expq_m(f32x4 s, float& lsum, int quad, int l15) {
    bf16x4 r;
#pragma unroll
    for (int i = 0; i < 4; ++i) {
        const float e = (quad * 4 + i <= l15) ? exp2f(s[i] * SCLF) : 0.f;
        r[i] = (bf16_t)e;
        lsum += (float)r[i];
    }
    return r;
}

typedef union { bf16x4 h; int u[2]; } pk2;
typedef union { int u[4]; bf16x8 v; } pk4u;

// C-layout (lane=query l15, keys quad*4+r in p0 / 16+quad*4+r in p1) ->
// A-layout (lane=query l15, keys quad*8..quad*8+7). Lane permutation among
// {i, i+16, i+32, i+48}: 8 bpermutes + 4 selects.
__device__ __forceinline__ bf16x8 xpose(bf16x4 p0, bf16x4 p1, int s0b, int s1b, bool lowsel) {
    pk2 a, b;
    a.h = p0; b.h = p1;
    const int x0 = __builtin_amdgcn_ds_bpermute(s0b, a.u[0]);
    const int y0 = __builtin_amdgcn_ds_bpermute(s0b, b.u[0]);
    const int x1 = __builtin_amdgcn_ds_bpermute(s0b, a.u[1]);
    const int y1 = __builtin_amdgcn_ds_bpermute(s0b, b.u[1]);
    const int x2 = __builtin_amdgcn_ds_bpermute(s1b, a.u[0]);
    const int y2 = __builtin_amdgcn_ds_bpermute(s1b, b.u[0]);
    const int x3 = __builtin_amdgcn_ds_bpermute(s1b, a.u[1]);
    const int y3 = __builtin_amdgcn_ds_bpermute(s1b, b.u[1]);
    pk4u r;
    r.u[0] = lowsel ? x0 : y0;
    r.u[1] = lowsel ? x1 : y1;
    r.u[2] = lowsel ? x2 : y2;
    r.u[3] = lowsel ? x3 : y3;
    return r.v;
}

// QK^T + softmax + transpose for one 32-key tile, 16 queries.
// MODE: 0 = full; 1 = even-diag (s0 masked, s1 all-masked -> skipped);
//       2 = odd-diag (s0 full, s1 masked).
template <int MODE>
__device__ __forceinline__ void qk16(
    const Kfrag& kf, int quad, int l15, int s0b, int s1b, bool lowsel,
    const bf16x8& qa0, const bf16x8& qa1,
    bf16x8& pfa, float& la)
{
    const f32x4 Z = (f32x4){0.f, 0.f, 0.f, 0.f};
    f32x4 s0 = Z, s1 = Z;
    s0 = MFMA16(kf.k00, qa0, s0); s0 = MFMA16(kf.k01, qa1, s0);
    if (MODE != 1) {
        s1 = MFMA16(kf.k10, qa0, s1); s1 = MFMA16(kf.k11, qa1, s1);
    }
    bf16x4 p0, p1;
    if (MODE == 0) {
        p0 = expq(s0, la);
        p1 = expq(s1, la);
    } else if (MODE == 1) {
        p0 = expq_m(s0, la, quad, l15);
        p1 = (bf16x4){(bf16_t)0.f, (bf16_t)0.f, (bf16_t)0.f, (bf16_t)0.f};
    } else {
        p0 = expq(s0, la);
        p1 = expq_m(s1, la, quad, l15);
    }
    pfa = xpose(p0, p1, s0b, s1b, lowsel);
}

__device__ __forceinline__ void pv16(
    const bf16x8& pfa, const Vfrag& v, f32x4 (&oa)[4])
{
    oa[0] = MFMA16(pfa, v.v0, oa[0]);
    oa[1] = MFMA16(pfa, v.v1, oa[1]);
    oa[2] = MFMA16(pfa, v.v2, oa[2]);
    oa[3] = MFMA16(pfa, v.v3, oa[3]);
}

__global__ __launch_bounds__(256, 4) void attn_kernel(
    const bf16_t* __restrict__ qk, const bf16_t* __restrict__ vt,
    bf16_t* __restrict__ out)
{
    const int t    = threadIdx.x;
    const int wid  = t >> 6;
    const int lane = t & 63;
    const int quad = lane >> 4;
    const int l15  = lane & 15;

    const int bx = blockIdx.x;                   // 0..2047
    const int u  = bx & 255;                     // CU class
    const int v_ = bx >> 8;                      // 0..7

    const int bh = ((u & 15) << 2) | (v_ & 3);   // 0..63; bx&7 const per bh
    const int c  = u >> 4;                       // 0..15
    const int vh = v_ >> 2;                      // 0..1
    const int hi = vh ? (7 - wid) : wid;         // SIMD s: {s, 7-s}
    const int cc = (hi & 1) ? (15 - c) : c;
    const int qt = (hi << 4) | cc;               // 0..127; per-SIMD sum const
    const int b  = bh >> 4;
    const int h  = bh & 15;
    const int q0 = qt << 4;

    // bpermute source lanes (byte indices)
    const int s0b = ((((quad << 1)) & 3) * 16 + l15) << 2;
    const int s1b = ((((quad << 1) + 1) & 3) * 16 + l15) << 2;
    const bool lowsel = quad < 2;

    const bf16_t* Qp = qk + (size_t)(b * 2048 + q0 + l15) * 2048 + h * 64 + quad * 8;
    const bf16x8 qa0 = ld8(Qp);
    const bf16x8 qa1 = ld8(Qp + 32);

    const bf16_t* Kbase = qk + (size_t)(b * 2048 + l15) * 2048 + 1024 + h * 64 + quad * 8;
    const bf16_t* Vbase = vt + ((size_t)bh * 64 + l15) * 2048 + quad * 8;

    f32x4 oa[4];
#pragma unroll
    for (int v = 0; v < 4; ++v) oa[v] = (f32x4){0.f, 0.f, 0.f, 0.f};
    float la = 0.f;

    const int nkb = (qt >> 1) + 1;   // 32-key tiles (last holds the diagonal)
    bf16x8 pfa;

    for (int kb = 0; kb < nkb - 1; ++kb) {
        const Kfrag kf = ldk(Kbase, kb << 5);
        keep(kf.k00); keep(kf.k01); keep(kf.k10); keep(kf.k11);  // MLP=4 pin
        const Vfrag vf = ldv(Vbase, kb << 5);    // issued early; used after SM
        qk16<0>(kf, quad, l15, s0b, s1b, lowsel, qa0, qa1, pfa, la);
        keep(vf.v0); keep(vf.v1); keep(vf.v2); keep(vf.v3);      // MLP=4 pin
        pv16(pfa, vf, oa);
    }
    // diagonal tile (dispatch on qt parity: even -> MODE 1, odd -> MODE 2)
    {
        const Kfrag kf = ldk(Kbase, (nkb - 1) << 5);
        keep(kf.k00); keep(kf.k01); keep(kf.k10); keep(kf.k11);
        const Vfrag vf = ldv(Vbase, (nkb - 1) << 5);
        if (qt & 1)
            qk16<2>(kf, quad, l15, s0b, s1b, lowsel, qa0, qa1, pfa, la);
        else
            qk16<1>(kf, quad, l15, s0b, s1b, lowsel, qa0, qa1, pfa, la);
        keep(vf.v0); keep(vf.v1); keep(vf.v2); keep(vf.v3);
        pv16(pfa, vf, oa);
    }

    // l: sum the 4 quad replicas (lanes i, i+16, i+32, i+48)
    la += __shfl_xor(la, 16); la += __shfl_xor(la, 32);
    const float inva = 1.0f / la;

    const size_t obase = (size_t)(b * 2048 + q0 + quad * 4) * 1024 + h * 64 + l15;
#pragma unroll
    for (int r = 0; r < 4; ++r) {
        const float ia = __shfl(inva, quad * 4 + r);
#pragma unroll
        for (int v = 0; v < 4; ++v)
            out[obase + (size_t)r * 1024 + v * 16] = (bf16_t)(oa[v][r] * ia);
    }
}

// fp32-visible stamp if the workspace is too small.
__global__ void ws_check_kernel(float* out, int code) {
    if (code != 0 && threadIdx.x == 0) out[0] = (float)code;
}

// ---------------------------------------------------------------------------
extern "C" void kernel_launch(void* const* d_in, const int* in_sizes, int n_in,
                              void* d_out, int out_size, void* d_ws, size_t ws_size,
                              hipStream_t stream)
{
    const void* x    = d_in[0];   // [4,2048,1024]
    const void* wqkv = d_in[1];   // [3072,1024]
    const void* wout = d_in[2];   // [1024,1024]

    // ws: qk 32MB | vt 16MB | attnbuf 16MB = 64MB
    bf16_t* qkbuf   = (bf16_t*)d_ws;
    bf16_t* vtbuf   = qkbuf + (size_t)8192 * 2048;
    bf16_t* attnbuf = vtbuf + (size_t)64 * 64 * 2048;
    float*  outp    = (float*)d_out;

    // scratch aliases (see buffer plan at top)
    bf16_t* xb  = attnbuf;            // 16MB, dead before attn writes attnbuf
    bf16_t* wqb = (bf16_t*)d_out;     // 6MB in d_out, dead before gemm2 writes
    bf16_t* wob = vtbuf;              // 2MB in vt region, converted after attn

    const int wsBad = (ws_size < (size_t)64 * 1024 * 1024) ? 512 : 0;

    // 0) convert x, W_qkv to bf16 (ballot probe: fp32 or bf16 inputs)
    cvt_big_kernel<<<5632, 256, 0, stream>>>(x, wqkv, xb, wqb);

    // 1) QKV projection (bf16 fast path): split Q|K + V^T
    gemm_bt_lds<1><<<dim3(24, 64), 256, 0, stream>>>(
        xb, wqb, qkbuf, vtbuf, 8192, 3072, 1024);

    // 2) causal flash attention: 2048 blocks x 4 waves, QBLK=16
    attn_kernel<<<2048, 256, 0, stream>>>(qkbuf, vtbuf, attnbuf);

    // 3) convert W_out (vt region now dead)
    cvt_small_kernel<<<512, 256, 0, stream>>>(wout, wob);

    // 4) output projection -> fp32 d_out (overwrites wqb scratch)
    gemm_bt_lds<0><<<dim3(8, 64), 256, 0, stream>>>(
        attnbuf, wob, outp, nullptr, 8192, 1024, 1024);

    ws_check_kernel<<<1, 64, 0, stream>>>(outp, wsBad);
}

// Round 11
// 364.377 us; speedup vs baseline: 1.2876x; 1.2876x over previous
//
#include <hip/hip_runtime.h>
#include <hip/hip_bf16.h>
#include <stdint.h>

// B=4, S=2048, D=1024, H=16, hd=64.
// Inputs fp32 or bf16 (wave-ballot probe in cvt kernels only); downstream is
// pure bf16. OUTPUT IS FLOAT32.
//
// Buffer plan (64MB ws + d_out-as-scratch):
//   ws:    qk 32MB | vt 16MB | attnbuf 16MB
//   xb  (16MB bf16) -> attnbuf region  (dead before attn writes it)
//   wqb ( 6MB bf16) -> d_out[0:6MB]    (dead before attn scratches d_out)
//   p1buf (16MB bf16) -> d_out[0:16MB] (attn half-1 partials; dead before gemm2)
//   lbuf0/1 (0.5MB each fp32) -> d_out[16MB:17MB]
//   wob ( 2MB bf16) -> vtbuf region    (converted after attn; vt dead then)

typedef __bf16 bf16_t;
typedef __attribute__((ext_vector_type(8))) __bf16 bf16x8;
typedef __attribute__((ext_vector_type(4))) __bf16 bf16x4;
typedef __attribute__((ext_vector_type(4))) float f32x4;

#define LOG2E 1.44269504088896340736f
#define SCLF (0.125f * LOG2E)
#define MFMA16(a, b, c) __builtin_amdgcn_mfma_f32_16x16x32_bf16(a, b, c, 0, 0, 0)

__device__ __forceinline__ bf16x8 ld8(const bf16_t* p) {
    return *(const bf16x8*)p;
}
__device__ __forceinline__ bf16x8 cvt8(const float* p) {
    f32x4 a = *(const f32x4*)p;
    f32x4 b = *(const f32x4*)(p + 4);
    bf16x8 r;
    r[0] = (bf16_t)a[0]; r[1] = (bf16_t)a[1]; r[2] = (bf16_t)a[2]; r[3] = (bf16_t)a[3];
    r[4] = (bf16_t)b[0]; r[5] = (bf16_t)b[1]; r[6] = (bf16_t)b[2]; r[7] = (bf16_t)b[3];
    return r;
}

// dtype probe, wave-cooperative: ONE coalesced load per lane + ballot.
__device__ __forceinline__ bool probe_f32_wave(const void* w) {
    const uint16_t* u = (const uint16_t*)w;
    const int lane = threadIdx.x & 63;
    const int e = (u[lane] >> 7) & 0xFF;
    const unsigned long long m = __ballot(e >= 96 && e <= 150);
    return __popcll(m) < 56;
}

// async global->LDS, 16B per lane. LDS dest: wave-uniform base + lane*16.
__device__ __forceinline__ void gll16(const bf16_t* g, bf16_t* l) {
    __builtin_amdgcn_global_load_lds(
        (const __attribute__((address_space(1))) void*)g,
        (__attribute__((address_space(3))) void*)l, 16, 0, 0);
}

// ---------------------------------------------------------------------------
// Input conversion (fp32->bf16, or bf16 copy), 8 elems/thread.
// ---------------------------------------------------------------------------
__global__ __launch_bounds__(256) void cvt_big_kernel(
    const void* __restrict__ x, const void* __restrict__ wq,
    bf16_t* __restrict__ xb, bf16_t* __restrict__ wqb)
{
    const int gid = blockIdx.x * 256 + threadIdx.x;
    const void* src;
    bf16_t* dst;
    int off;
    if (gid < 1048576) { src = x;  dst = xb;  off = gid; }
    else               { src = wq; dst = wqb; off = gid - 1048576; }
    const bool f32 = probe_f32_wave(src);
    const bf16x8 v = f32 ? cvt8((const float*)src + (size_t)off * 8)
                         : ld8((const bf16_t*)src + (size_t)off * 8);
    *(bf16x8*)(dst + (size_t)off * 8) = v;
}

__global__ __launch_bounds__(256) void cvt_small_kernel(
    const void* __restrict__ wo, bf16_t* __restrict__ wob)
{
    const int off = blockIdx.x * 256 + threadIdx.x;
    const bool f32 = probe_f32_wave(wo);
    const bf16x8 v = f32 ? cvt8((const float*)wo + (size_t)off * 8)
                         : ld8((const bf16_t*)wo + (size_t)off * 8);
    *(bf16x8*)(wob + (size_t)off * 8) = v;
}

// ---------------------------------------------------------------------------
// GEMM (pure bf16): C = A[M,K] @ B[N,K]^T, 128x128 tile, BK=32,
// global_load_lds width-16 staging (m97 structure) + bijective XCD swizzle.
// EPI==0: C float*, plain [M,N]. EPI==1: C bf16* Q|K split + VT scatter.
// ---------------------------------------------------------------------------
template <int EPI>
__global__ __launch_bounds__(256) void gemm_bt_lds(
    const bf16_t* __restrict__ A, const bf16_t* __restrict__ B,
    void* __restrict__ C, bf16_t* __restrict__ VT,
    int M, int N, int K)
{
    __shared__ __align__(16) bf16_t lsA[128 * 32];
    __shared__ __align__(16) bf16_t lsB[128 * 32];

    const int t    = threadIdx.x;
    const int lane = t & 63;
    const int wid  = t >> 6;
    const int quad = lane >> 4;
    const int l15  = lane & 15;
    const int wm   = (wid & 1) * 64;
    const int wn   = (wid >> 1) * 64;

    const int nbx = gridDim.x;
    const int nwg = nbx * gridDim.y;
    const int bid = blockIdx.y * nbx + blockIdx.x;
    const int sid = (bid & 7) * (nwg >> 3) + (bid >> 3);
    const int m0  = (sid / nbx) * 128;
    const int n0  = (sid % nbx) * 128;

    const bf16_t* Ar = A + (size_t)(m0 + (t >> 2)) * K + (t & 3) * 8;
    const bf16_t* Br = B + (size_t)(n0 + (t >> 2)) * K + (t & 3) * 8;
    bf16_t* la = lsA + t * 8;
    bf16_t* lb = lsB + t * 8;

    f32x4 acc[4][4];
#pragma unroll
    for (int i = 0; i < 4; ++i)
#pragma unroll
        for (int j = 0; j < 4; ++j) acc[i][j] = (f32x4){0.f, 0.f, 0.f, 0.f};

    for (int k0 = 0; k0 < K; k0 += 32) {
        __syncthreads();
        gll16(Ar + k0, la);
        gll16(Ar + (size_t)64 * K + k0, la + 2048);
        gll16(Br + k0, lb);
        gll16(Br + (size_t)64 * K + k0, lb + 2048);
        __syncthreads();

        bf16x8 af[4], bfr[4];
#pragma unroll
        for (int i = 0; i < 4; ++i)
            af[i] = ld8(lsA + (wm + i * 16 + l15) * 32 + quad * 8);
#pragma unroll
        for (int j = 0; j < 4; ++j)
            bfr[j] = ld8(lsB + (wn + j * 16 + l15) * 32 + quad * 8);
#pragma unroll
        for (int i = 0; i < 4; ++i)
#pragma unroll
            for (int j = 0; j < 4; ++j)
                acc[i][j] = MFMA16(af[i], bfr[j], acc[i][j]);
    }

#pragma unroll
    for (int i = 0; i < 4; ++i) {
        const int row = m0 + wm + i * 16 + quad * 4;
#pragma unroll
        for (int j = 0; j < 4; ++j) {
            const int col = n0 + wn + j * 16 + l15;
#pragma unroll
            for (int r = 0; r < 4; ++r) {
                const int rr = row + r;
                if (EPI == 0) {
                    ((float*)C)[(size_t)rr * N + col] = acc[i][j][r];
                } else {
                    const bf16_t v = (bf16_t)acc[i][j][r];
                    if (col < 2048) {
                        ((bf16_t*)C)[(size_t)rr * 2048 + col] = v;
                    } else {
                        const int c2 = col - 2048;
                        const int h = c2 >> 6, d = c2 & 63;
                        const int b = rr >> 11, s = rr & 2047;
                        VT[((size_t)((b << 4) + h) * 64 + d) * 2048 + s] = v;
                    }
                }
            }
        }
    }
}

// ---------------------------------------------------------------------------
// Flash attention (causal), NO-RESCALE, QBLK=32, R5's exact deferred-PV
// pipeline (the only codegen measured healthy: VGPR 56, 134us), with
// BLOCK-LEVEL split-K: task (bh,qt) split into half 0 = key tiles [0,mid)
// and half 1 = [mid,qt] (mid=(qt+1)/2). Halves are independent BLOCKS (no
// barrier coupling — R3's bug; no register caps — R7-R10's bug). Partials
// are exactly additive (no-rescale): un-normalized O in bf16 + l in fp32;
// merged by a tiny elementwise kernel. 2048 blocks -> 8 waves/SIMD
// launched; critical path <=33 steps; per-SIMD step-sum = 130 (const);
// bh XCD-affine as before.
// ---------------------------------------------------------------------------
struct Kfrag { bf16x8 k00, k01, k10, k11; };
struct Vfrag { bf16x8 v0, v1, v2, v3; };

__device__ __forceinline__ Kfrag ldk(const bf16_t* Kbase, int key0) {
    const bf16_t* kp = Kbase + (size_t)key0 * 2048;
    Kfrag f;
    f.k00 = ld8(kp);
    f.k01 = ld8(kp + 32);
    f.k10 = ld8(kp + (size_t)16 * 2048);
    f.k11 = ld8(kp + (size_t)16 * 2048 + 32);
    return f;
}
__device__ __forceinline__ Vfrag ldv(const bf16_t* Vbase, int key0) {
    const bf16_t* vp = Vbase + key0;
    Vfrag f;
    f.v0 = ld8(vp);
    f.v1 = ld8(vp + (size_t)16 * 2048);
    f.v2 = ld8(vp + (size_t)32 * 2048);
    f.v3 = ld8(vp + (size_t)48 * 2048);
    return f;
}

__device__ __forceinline__ bf16x4 expq(f32x4 s, float& lsum) {
    bf16x4 r;
#pragma unroll
    for (int i = 0; i < 4; ++i) {
        const float e = exp2f(s[i] * SCLF);
        r[i] = (bf16_t)e;
        lsum += (float)r[i];
    }
    return r;
}
__device__ __forceinline__ bf16x4 expq_m(f32x4 s, float& lsum, int quad, int l15) {
    bf16x4 r;
#pragma unroll
    for (int i = 0; i < 4; ++i) {
        const float e = (quad * 4 + i <= l15) ? exp2f(s[i] * SCLF) : 0.f;
        r[i] = (bf16_t)e;
        lsum += (float)r[i];
    }
    return r;
}

typedef union { bf16x4 h; int u[2]; } pk2;
typedef union { int u[4]; bf16x8 v; } pk4u;

// C-layout -> A-layout P transpose: lane permutation among {i,i+16,i+32,i+48}.
__device__ __forceinline__ bf16x8 xpose(bf16x4 p0, bf16x4 p1, int s0b, int s1b, bool lowsel) {
    pk2 a, b;
    a.h = p0; b.h = p1;
    const int x0 = __builtin_amdgcn_ds_bpermute(s0b, a.u[0]);
    const int y0 = __builtin_amdgcn_ds_bpermute(s0b, b.u[0]);
    const int x1 = __builtin_amdgcn_ds_bpermute(s0b, a.u[1]);
    const int y1 = __builtin_amdgcn_ds_bpermute(s0b, b.u[1]);
    const int x2 = __builtin_amdgcn_ds_bpermute(s1b, a.u[0]);
    const int y2 = __builtin_amdgcn_ds_bpermute(s1b, b.u[0]);
    const int x3 = __builtin_amdgcn_ds_bpermute(s1b, a.u[1]);
    const int y3 = __builtin_amdgcn_ds_bpermute(s1b, b.u[1]);
    pk4u r;
    r.u[0] = lowsel ? x0 : y0;
    r.u[1] = lowsel ? x1 : y1;
    r.u[2] = lowsel ? x2 : y2;
    r.u[3] = lowsel ? x3 : y3;
    return r.v;
}

// QK^T + softmax + transpose for one 32-key tile -> P fragments (pfa, pfb).
template <int DIAG>
__device__ __forceinline__ void qk_phase(
    const Kfrag& kf, int quad, int l15, int s0b, int s1b, bool lowsel,
    const bf16x8& qa0, const bf16x8& qa1, const bf16x8& qb0, const bf16x8& qb1,
    bf16x8& pfa, bf16x8& pfb, float& la, float& lb)
{
    const f32x4 Z = (f32x4){0.f, 0.f, 0.f, 0.f};
    f32x4 s0a = Z, s1a = Z, s0b_ = Z, s1b_ = Z;
    s0a = MFMA16(kf.k00, qa0, s0a); s0a = MFMA16(kf.k01, qa1, s0a);
    s0b_ = MFMA16(kf.k00, qb0, s0b_); s0b_ = MFMA16(kf.k01, qb1, s0b_);
    if (!DIAG) {
        s1a = MFMA16(kf.k10, qa0, s1a); s1a = MFMA16(kf.k11, qa1, s1a);
    }
    s1b_ = MFMA16(kf.k10, qb0, s1b_); s1b_ = MFMA16(kf.k11, qb1, s1b_);

    bf16x4 pa0, pa1, pb0, pb1;
    if (DIAG) {
        pa0 = expq_m(s0a, la, quad, l15);
        pa1 = (bf16x4){(bf16_t)0.f, (bf16_t)0.f, (bf16_t)0.f, (bf16_t)0.f};
        pb0 = expq(s0b_, lb);
        pb1 = expq_m(s1b_, lb, quad, l15);
    } else {
        pa0 = expq(s0a, la); pa1 = expq(s1a, la);
        pb0 = expq(s0b_, lb); pb1 = expq(s1b_, lb);
    }
    pfa = xpose(pa0, pa1, s0b, s1b, lowsel);
    pfb = xpose(pb0, pb1, s0b, s1b, lowsel);
}

__device__ __forceinline__ void pv(
    const bf16x8& pfa, const bf16x8& pfb, const Vfrag& v,
    f32x4 (&oa)[4], f32x4 (&ob)[4])
{
    oa[0] = MFMA16(pfa, v.v0, oa[0]); ob[0] = MFMA16(pfb, v.v0, ob[0]);
    oa[1] = MFMA16(pfa, v.v1, oa[1]); ob[1] = MFMA16(pfb, v.v1, ob[1]);
    oa[2] = MFMA16(pfa, v.v2, oa[2]); ob[2] = MFMA16(pfb, v.v2, ob[2]);
    oa[3] = MFMA16(pfa, v.v3, oa[3]); ob[3] = MFMA16(pfb, v.v3, ob[3]);
}

__global__ __launch_bounds__(256, 4) void attn_kernel(
    const bf16_t* __restrict__ qk, const bf16_t* __restrict__ vt,
    bf16_t* __restrict__ p0buf, bf16_t* __restrict__ p1buf,
    float* __restrict__ lbuf0, float* __restrict__ lbuf1)
{
    const int t    = threadIdx.x;
    const int wid  = t >> 6;
    const int lane = t & 63;
    const int quad = lane >> 4;
    const int l15  = lane & 15;

    const int bx = blockIdx.x;                   // 0..2047
    const int u  = bx & 255;                     // CU class
    const int v_ = bx >> 8;                      // 0..7
    const int bh = ((u & 15) << 2) | wid;        // 0..63, XCD-affine
    const int c  = u >> 4;                       // 0..15
    const int v2 = v_ & 3;
    const int bs = (v2 & 1) ? (31 - c) : c;
    const int qt = bs + ((v2 >> 1) << 5);        // 0..63 (R5 mapping)
    const int half = v_ >> 2;                    // split-K half
    const int b  = bh >> 4;
    const int h  = bh & 15;
    const int q0 = qt << 5;

    const int mid = (qt + 1) >> 1;
    const int lo  = half ? mid : 0;
    const int hi  = half ? (qt + 1) : mid;       // tiles [lo, hi)
    const int cnt = hi - lo;

    // bpermute source lanes (byte indices)
    const int s0b = ((((quad << 1)) & 3) * 16 + l15) << 2;
    const int s1b = ((((quad << 1) + 1) & 3) * 16 + l15) << 2;
    const bool lowsel = quad < 2;

    const bf16_t* Qp = qk + (size_t)(b * 2048 + q0 + l15) * 2048 + h * 64 + quad * 8;
    const bf16x8 qa0 = ld8(Qp);
    const bf16x8 qa1 = ld8(Qp + 32);
    const bf16x8 qb0 = ld8(Qp + (size_t)16 * 2048);
    const bf16x8 qb1 = ld8(Qp + (size_t)16 * 2048 + 32);

    const bf16_t* Kbase = qk + (size_t)(b * 2048 + l15) * 2048 + 1024 + h * 64 + quad * 8;
    const bf16_t* Vbase = vt + ((size_t)bh * 64 + l15) * 2048 + quad * 8;

    f32x4 oa[4], ob[4];
#pragma unroll
    for (int v = 0; v < 4; ++v) {
        oa[v] = (f32x4){0.f, 0.f, 0.f, 0.f};
        ob[v] = (f32x4){0.f, 0.f, 0.f, 0.f};
    }
    float la = 0.f, lb = 0.f;

    if (cnt > 0) {
        Kfrag kc = ldk(Kbase, lo << 5);
        Vfrag vc = ldv(Vbase, lo << 5);
        bf16x8 pfa, pfb;

        if (cnt > 1) {
            // tile lo is always full here (lo <= hi-2 <= qt-1)
            Kfrag kn = ldk(Kbase, (lo + 1) << 5);
            qk_phase<0>(kc, quad, l15, s0b, s1b, lowsel,
                        qa0, qa1, qb0, qb1, pfa, pfb, la, lb);
            kc = kn;
            for (int kb = lo + 1; kb < hi - 1; ++kb) {
                Kfrag knn = ldk(Kbase, (kb + 1) << 5);
                Vfrag vn  = ldv(Vbase, kb << 5);
                pv(pfa, pfb, vc, oa, ob);        // PV[kb-1] (indep of exp)
                qk_phase<0>(kc, quad, l15, s0b, s1b, lowsel,
                            qa0, qa1, qb0, qb1, pfa, pfb, la, lb);
                kc = knn; vc = vn;
            }
            Vfrag vn = ldv(Vbase, (hi - 1) << 5);
            pv(pfa, pfb, vc, oa, ob);            // PV[hi-2]
            if (half)   // half 1's last tile is the diagonal (hi-1 == qt)
                qk_phase<1>(kc, quad, l15, s0b, s1b, lowsel,
                            qa0, qa1, qb0, qb1, pfa, pfb, la, lb);
            else        // half 0's last tile (mid-1 < qt) is full
                qk_phase<0>(kc, quad, l15, s0b, s1b, lowsel,
                            qa0, qa1, qb0, qb1, pfa, pfb, la, lb);
            vc = vn;
        } else {
            // single tile lo: diagonal iff lo == qt (half1 with qt<=1)
            if (lo == qt)
                qk_phase<1>(kc, quad, l15, s0b, s1b, lowsel,
                            qa0, qa1, qb0, qb1, pfa, pfb, la, lb);
            else
                qk_phase<0>(kc, quad, l15, s0b, s1b, lowsel,
                            qa0, qa1, qb0, qb1, pfa, pfb, la, lb);
        }
        pv(pfa, pfb, vc, oa, ob);                // flush last PV
    }

    // l: sum the 4 quad replicas (lanes i, i+16, i+32, i+48)
    la += __shfl_xor(la, 16); la += __shfl_xor(la, 32);
    lb += __shfl_xor(lb, 16); lb += __shfl_xor(lb, 32);

    // un-normalized partial O (bf16) + l (fp32) for this half
    bf16_t* pb = half ? p1buf : p0buf;
    const size_t obase = (size_t)(b * 2048 + q0 + quad * 4) * 1024 + h * 64 + l15;
#pragma unroll
    for (int r = 0; r < 4; ++r) {
#pragma unroll
        for (int v = 0; v < 4; ++v) {
            pb[obase + (size_t)r * 1024 + v * 16]        = (bf16_t)oa[v][r];
            pb[obase + (size_t)(16 + r) * 1024 + v * 16] = (bf16_t)ob[v][r];
        }
    }
    float* lf = half ? lbuf1 : lbuf0;
    if (quad == 0) {
        lf[(size_t)bh * 2048 + q0 + l15]      = la;
        lf[(size_t)bh * 2048 + q0 + 16 + l15] = lb;
    }
}

// merge: out = (p0 + p1) / (l0 + l1), elementwise, 8 elems/thread.
__global__ __launch_bounds__(256) void merge_kernel(
    const bf16_t* __restrict__ p1buf,
    const float* __restrict__ lbuf0, const float* __restrict__ lbuf1,
    bf16_t* __restrict__ p0buf)   // in-out: attnbuf
{
    const int gid = blockIdx.x * 256 + threadIdx.x;
    const size_t e0 = (size_t)gid * 8;
    const int row = (int)(e0 >> 10);
    const int col = (int)(e0 & 1023);
    const int b = row >> 11, s = row & 2047;
    const int h = col >> 6;
    const size_t li = (size_t)((b << 4) + h) * 2048 + s;
    const float inv = 1.0f / (lbuf0[li] + lbuf1[li]);
    const bf16x8 a = ld8(p0buf + e0);
    const bf16x8 c = ld8(p1buf + e0);
    bf16x8 o;
#pragma unroll
    for (int i = 0; i < 8; ++i)
        o[i] = (bf16_t)(((float)a[i] + (float)c[i]) * inv);
    *(bf16x8*)(p0buf + e0) = o;
}

// fp32-visible stamp if the workspace is too small.
__global__ void ws_check_kernel(float* out, int code) {
    if (code != 0 && threadIdx.x == 0) out[0] = (float)code;
}

// ---------------------------------------------------------------------------
extern "C" void kernel_launch(void* const* d_in, const int* in_sizes, int n_in,
                              void* d_out, int out_size, void* d_ws, size_t ws_size,
                              hipStream_t stream)
{
    const void* x    = d_in[0];   // [4,2048,1024]
    const void* wqkv = d_in[1];   // [3072,1024]
    const void* wout = d_in[2];   // [1024,1024]

    // ws: qk 32MB | vt 16MB | attnbuf 16MB = 64MB
    bf16_t* qkbuf   = (bf16_t*)d_ws;
    bf16_t* vtbuf   = qkbuf + (size_t)8192 * 2048;
    bf16_t* attnbuf = vtbuf + (size_t)64 * 64 * 2048;
    float*  outp    = (float*)d_out;

    // scratch aliases (see buffer plan at top)
    bf16_t* xb    = attnbuf;               // dead before attn writes partial0
    bf16_t* wqb   = (bf16_t*)d_out;        // dead before attn writes partial1
    bf16_t* p1buf = (bf16_t*)d_out;        // 16MB, dead before gemm2 writes
    float*  lbuf0 = (float*)((char*)d_out + (size_t)16 * 1024 * 1024);
    float*  lbuf1 = lbuf0 + (size_t)64 * 2048;
    bf16_t* wob   = vtbuf;                 // converted after attn; vt dead then

    const int wsBad = (ws_size < (size_t)64 * 1024 * 1024) ? 512 : 0;

    // 0) convert x, W_qkv to bf16 (ballot probe: fp32 or bf16 inputs)
    cvt_big_kernel<<<5632, 256, 0, stream>>>(x, wqkv, xb, wqb);

    // 1) QKV projection (bf16 fast path): split Q|K + V^T
    gemm_bt_lds<1><<<dim3(24, 64), 256, 0, stream>>>(
        xb, wqb, qkbuf, vtbuf, 8192, 3072, 1024);

    // 2) causal flash attention, block-level split-K: 2048 blocks x 4 waves
    attn_kernel<<<2048, 256, 0, stream>>>(qkbuf, vtbuf, attnbuf, p1buf,
                                          lbuf0, lbuf1);

    // 3) merge halves: attnbuf = (p0+p1)/(l0+l1)
    merge_kernel<<<4096, 256, 0, stream>>>(p1buf, lbuf0, lbuf1, attnbuf);

    // 4) convert W_out (vt region now dead)
    cvt_small_kernel<<<512, 256, 0, stream>>>(wout, wob);

    // 5) output projection -> fp32 d_out (overwrites p1buf/lbuf scratch)
    gemm_bt_lds<0><<<dim3(8, 64), 256, 0, stream>>>(
        attnbuf, wob, outp, nullptr, 8192, 1024, 1024);

    ws_check_kernel<<<1, 64, 0, stream>>>(outp, wsBad);
}

// Round 12
// 304.574 us; speedup vs baseline: 1.5404x; 1.1964x over previous
//
#include <hip/hip_runtime.h>
#include <hip/hip_bf16.h>
#include <stdint.h>

// B=4, S=2048, D=1024, H=16, hd=64.
// Inputs fp32 or bf16 (wave-ballot probe in cvt kernels only); downstream is
// pure bf16. OUTPUT IS FLOAT32.
//
// Buffer plan (64MB ws + d_out-as-scratch):
//   ws:    qk 32MB | vt 16MB | attnbuf 16MB
//   xb  (16MB bf16) -> attnbuf region  (dead before attn writes it)
//   wqb ( 6MB bf16) -> d_out scratch   (read by gemm1 only; gemm1 writes ws)
//   wob ( 2MB bf16) -> vtbuf region    (converted after attn; vt dead then)

typedef __bf16 bf16_t;
typedef __attribute__((ext_vector_type(8))) __bf16 bf16x8;
typedef __attribute__((ext_vector_type(4))) __bf16 bf16x4;
typedef __attribute__((ext_vector_type(4))) float f32x4;

#define LOG2E 1.44269504088896340736f
#define SCLF (0.125f * LOG2E)
#define MFMA16(a, b, c) __builtin_amdgcn_mfma_f32_16x16x32_bf16(a, b, c, 0, 0, 0)

__device__ __forceinline__ bf16x8 ld8(const bf16_t* p) {
    return *(const bf16x8*)p;
}
__device__ __forceinline__ bf16x8 cvt8(const float* p) {
    f32x4 a = *(const f32x4*)p;
    f32x4 b = *(const f32x4*)(p + 4);
    bf16x8 r;
    r[0] = (bf16_t)a[0]; r[1] = (bf16_t)a[1]; r[2] = (bf16_t)a[2]; r[3] = (bf16_t)a[3];
    r[4] = (bf16_t)b[0]; r[5] = (bf16_t)b[1]; r[6] = (bf16_t)b[2]; r[7] = (bf16_t)b[3];
    return r;
}

// dtype probe, wave-cooperative: ONE coalesced load per lane + ballot.
__device__ __forceinline__ bool probe_f32_wave(const void* w) {
    const uint16_t* u = (const uint16_t*)w;
    const int lane = threadIdx.x & 63;
    const int e = (u[lane] >> 7) & 0xFF;
    const unsigned long long m = __ballot(e >= 96 && e <= 150);
    return __popcll(m) < 56;
}

// async global->LDS, 16B per lane. LDS dest: wave-uniform base + lane*16.
__device__ __forceinline__ void gll16(const bf16_t* g, bf16_t* l) {
    __builtin_amdgcn_global_load_lds(
        (const __attribute__((address_space(1))) void*)g,
        (__attribute__((address_space(3))) void*)l, 16, 0, 0);
}

// ---------------------------------------------------------------------------
// Input conversion (fp32->bf16, or bf16 copy), 8 elems/thread.
// ---------------------------------------------------------------------------
__global__ __launch_bounds__(256) void cvt_big_kernel(
    const void* __restrict__ x, const void* __restrict__ wq,
    bf16_t* __restrict__ xb, bf16_t* __restrict__ wqb)
{
    const int gid = blockIdx.x * 256 + threadIdx.x;
    const void* src;
    bf16_t* dst;
    int off;
    if (gid < 1048576) { src = x;  dst = xb;  off = gid; }
    else               { src = wq; dst = wqb; off = gid - 1048576; }
    const bool f32 = probe_f32_wave(src);
    const bf16x8 v = f32 ? cvt8((const float*)src + (size_t)off * 8)
                         : ld8((const bf16_t*)src + (size_t)off * 8);
    *(bf16x8*)(dst + (size_t)off * 8) = v;
}

__global__ __launch_bounds__(256) void cvt_small_kernel(
    const void* __restrict__ wo, bf16_t* __restrict__ wob)
{
    const int off = blockIdx.x * 256 + threadIdx.x;
    const bool f32 = probe_f32_wave(wo);
    const bf16x8 v = f32 ? cvt8((const float*)wo + (size_t)off * 8)
                         : ld8((const bf16_t*)wo + (size_t)off * 8);
    *(bf16x8*)(wob + (size_t)off * 8) = v;
}

// ---------------------------------------------------------------------------
// GEMM (pure bf16): C = A[M,K] @ B[N,K]^T, 128x128 tile, BK=64 (two 32-K
// halves per barrier pair -> half the drain count vs BK=32), global_load_lds
// width-16 staging + bijective XCD swizzle.
// LDS layout per matrix: [half(2)][128 rows][32 cols] = 16KB, linear so the
// gll16 wave-uniform-dest constraint holds.
// EPI==0: C float*, plain [M,N]. EPI==1: C bf16* Q|K split + VT scatter
// (VT: 4 contiguous-s rows packed into one 8B bf16x4 store).
// ---------------------------------------------------------------------------
template <int EPI>
__global__ __launch_bounds__(256) void gemm_bt_lds(
    const bf16_t* __restrict__ A, const bf16_t* __restrict__ B,
    void* __restrict__ C, bf16_t* __restrict__ VT,
    int M, int N, int K)
{
    __shared__ __align__(16) bf16_t lsA[2 * 128 * 32];
    __shared__ __align__(16) bf16_t lsB[2 * 128 * 32];

    const int t    = threadIdx.x;
    const int lane = t & 63;
    const int wid  = t >> 6;
    const int quad = lane >> 4;
    const int l15  = lane & 15;
    const int wm   = (wid & 1) * 64;
    const int wn   = (wid >> 1) * 64;

    // XCD-aware bijective swizzle (nwg % 8 == 0: 1536 / 512).
    const int nbx = gridDim.x;
    const int nwg = nbx * gridDim.y;
    const int bid = blockIdx.y * nbx + blockIdx.x;
    const int sid = (bid & 7) * (nwg >> 3) + (bid >> 3);
    const int m0  = (sid / nbx) * 128;
    const int n0  = (sid % nbx) * 128;

    f32x4 acc[4][4];
#pragma unroll
    for (int i = 0; i < 4; ++i)
#pragma unroll
        for (int j = 0; j < 4; ++j) acc[i][j] = (f32x4){0.f, 0.f, 0.f, 0.f};

    for (int k0 = 0; k0 < K; k0 += 64) {
        __syncthreads();   // previous tile's readers done
        // staging call j: rows (j&1)*64 + t>>2, k-half j>>1, chunk t&3.
        // LDS dest j*2048 + t*8 elems == linear [half][row][32] layout.
#pragma unroll
        for (int j = 0; j < 4; ++j) {
            const int row = (j & 1) * 64 + (t >> 2);
            const int col = k0 + (j >> 1) * 32 + (t & 3) * 8;
            gll16(A + (size_t)(m0 + row) * K + col, lsA + j * 2048 + t * 8);
            gll16(B + (size_t)(n0 + row) * K + col, lsB + j * 2048 + t * 8);
        }
        __syncthreads();   // compiler drains vmcnt before s_barrier

#pragma unroll 1
        for (int h = 0; h < 2; ++h) {   // unroll 1: cap VGPR (protect occupancy)
            bf16x8 af[4], bfr[4];
#pragma unroll
            for (int i = 0; i < 4; ++i)
                af[i] = ld8(lsA + h * 4096 + (wm + i * 16 + l15) * 32 + quad * 8);
#pragma unroll
            for (int j = 0; j < 4; ++j)
                bfr[j] = ld8(lsB + h * 4096 + (wn + j * 16 + l15) * 32 + quad * 8);
#pragma unroll
            for (int i = 0; i < 4; ++i)
#pragma unroll
                for (int j = 0; j < 4; ++j)
                    acc[i][j] = MFMA16(af[i], bfr[j], acc[i][j]);
        }
    }

#pragma unroll
    for (int i = 0; i < 4; ++i) {
        const int row = m0 + wm + i * 16 + quad * 4;
#pragma unroll
        for (int j = 0; j < 4; ++j) {
            const int col = n0 + wn + j * 16 + l15;
            if (EPI == 0) {
#pragma unroll
                for (int r = 0; r < 4; ++r)
                    ((float*)C)[(size_t)(row + r) * N + col] = acc[i][j][r];
            } else if (col < 2048) {
#pragma unroll
                for (int r = 0; r < 4; ++r)
                    ((bf16_t*)C)[(size_t)(row + r) * 2048 + col] = (bf16_t)acc[i][j][r];
            } else {
                // VT[(b*16+h)*64+d][s]: rows are contiguous in s -> 8B pack.
                const int c2 = col - 2048;
                const int h = c2 >> 6, d = c2 & 63;
                const int b = row >> 11, s = row & 2047;
                bf16x4 pk;
#pragma unroll
                for (int r = 0; r < 4; ++r) pk[r] = (bf16_t)acc[i][j][r];
                *(bf16x4*)(VT + ((size_t)((b << 4) + h) * 64 + d) * 2048 + s) = pk;
            }
        }
    }
}

// ---------------------------------------------------------------------------
// Flash attention (causal), NO-RESCALE, QBLK=32/wave — R5's exact kernel
// (measured: VGPR 56, 134us, the best attn of the session). Deferred-PV
// pipeline; bpermute P-transpose; R2 task mapping (1024 blocks x 4 waves,
// per-SIMD step-sum constant, bh XCD-affine). Rounds 6-11 established that
// more waves do NOT help (L2-footprint-limited, not occupancy-limited).
// ---------------------------------------------------------------------------
struct Kfrag { bf16x8 k00, k01, k10, k11; };
struct Vfrag { bf16x8 v0, v1, v2, v3; };

__device__ __forceinline__ Kfrag ldk(const bf16_t* Kbase, int key0) {
    const bf16_t* kp = Kbase + (size_t)key0 * 2048;
    Kfrag f;
    f.k00 = ld8(kp);
    f.k01 = ld8(kp + 32);
    f.k10 = ld8(kp + (size_t)16 * 2048);
    f.k11 = ld8(kp + (size_t)16 * 2048 + 32);
    return f;
}
__device__ __forceinline__ Vfrag ldv(const bf16_t* Vbase, int key0) {
    const bf16_t* vp = Vbase + key0;
    Vfrag f;
    f.v0 = ld8(vp);
    f.v1 = ld8(vp + (size_t)16 * 2048);
    f.v2 = ld8(vp + (size_t)32 * 2048);
    f.v3 = ld8(vp + (size_t)48 * 2048);
    return f;
}

__device__ __forceinline__ bf16x4 expq(f32x4 s, float& lsum) {
    bf16x4 r;
#pragma unroll
    for (int i = 0; i < 4; ++i) {
        const float e = exp2f(s[i] * SCLF);
        r[i] = (bf16_t)e;
        lsum += (float)r[i];
    }
    return r;
}
__device__ __forceinline__ bf16x4 expq_m(f32x4 s, float& lsum, int quad, int l15) {
    bf16x4 r;
#pragma unroll
    for (int i = 0; i < 4; ++i) {
        const float e = (quad * 4 + i <= l15) ? exp2f(s[i] * SCLF) : 0.f;
        r[i] = (bf16_t)e;
        lsum += (float)r[i];
    }
    return r;
}

typedef union { bf16x4 h; int u[2]; } pk2;
typedef union { int u[4]; bf16x8 v; } pk4u;

// C-layout -> A-layout P transpose: lane permutation among {i,i+16,i+32,i+48}.
__device__ __forceinline__ bf16x8 xpose(bf16x4 p0, bf16x4 p1, int s0b, int s1b, bool lowsel) {
    pk2 a, b;
    a.h = p0; b.h = p1;
    const int x0 = __builtin_amdgcn_ds_bpermute(s0b, a.u[0]);
    const int y0 = __builtin_amdgcn_ds_bpermute(s0b, b.u[0]);
    const int x1 = __builtin_amdgcn_ds_bpermute(s0b, a.u[1]);
    const int y1 = __builtin_amdgcn_ds_bpermute(s0b, b.u[1]);
    const int x2 = __builtin_amdgcn_ds_bpermute(s1b, a.u[0]);
    const int y2 = __builtin_amdgcn_ds_bpermute(s1b, b.u[0]);
    const int x3 = __builtin_amdgcn_ds_bpermute(s1b, a.u[1]);
    const int y3 = __builtin_amdgcn_ds_bpermute(s1b, b.u[1]);
    pk4u r;
    r.u[0] = lowsel ? x0 : y0;
    r.u[1] = lowsel ? x1 : y1;
    r.u[2] = lowsel ? x2 : y2;
    r.u[3] = lowsel ? x3 : y3;
    return r.v;
}

// QK^T + softmax + transpose for one 32-key tile -> P fragments (pfa, pfb).
template <int DIAG>
__device__ __forceinline__ void qk_phase(
    const Kfrag& kf, int quad, int l15, int s0b, int s1b, bool lowsel,
    const bf16x8& qa0, const bf16x8& qa1, const bf16x8& qb0, const bf16x8& qb1,
    bf16x8& pfa, bf16x8& pfb, float& la, float& lb)
{
    const f32x4 Z = (f32x4){0.f, 0.f, 0.f, 0.f};
    f32x4 s0a = Z, s1a = Z, s0b_ = Z, s1b_ = Z;
    s0a = MFMA16(kf.k00, qa0, s0a); s0a = MFMA16(kf.k01, qa1, s0a);
    s0b_ = MFMA16(kf.k00, qb0, s0b_); s0b_ = MFMA16(kf.k01, qb1, s0b_);
    if (!DIAG) {
        s1a = MFMA16(kf.k10, qa0, s1a); s1a = MFMA16(kf.k11, qa1, s1a);
    }
    s1b_ = MFMA16(kf.k10, qb0, s1b_); s1b_ = MFMA16(kf.k11, qb1, s1b_);

    bf16x4 pa0, pa1, pb0, pb1;
    if (DIAG) {
        pa0 = expq_m(s0a, la, quad, l15);
        pa1 = (bf16x4){(bf16_t)0.f, (bf16_t)0.f, (bf16_t)0.f, (bf16_t)0.f};
        pb0 = expq(s0b_, lb);
        pb1 = expq_m(s1b_, lb, quad, l15);
    } else {
        pa0 = expq(s0a, la); pa1 = expq(s1a, la);
        pb0 = expq(s0b_, lb); pb1 = expq(s1b_, lb);
    }
    pfa = xpose(pa0, pa1, s0b, s1b, lowsel);
    pfb = xpose(pb0, pb1, s0b, s1b, lowsel);
}

__device__ __forceinline__ void pv(
    const bf16x8& pfa, const bf16x8& pfb, const Vfrag& v,
    f32x4 (&oa)[4], f32x4 (&ob)[4])
{
    oa[0] = MFMA16(pfa, v.v0, oa[0]); ob[0] = MFMA16(pfb, v.v0, ob[0]);
    oa[1] = MFMA16(pfa, v.v1, oa[1]); ob[1] = MFMA16(pfb, v.v1, ob[1]);
    oa[2] = MFMA16(pfa, v.v2, oa[2]); ob[2] = MFMA16(pfb, v.v2, ob[2]);
    oa[3] = MFMA16(pfa, v.v3, oa[3]); ob[3] = MFMA16(pfb, v.v3, ob[3]);
}

__global__ __launch_bounds__(256, 4) void attn_kernel(
    const bf16_t* __restrict__ qk, const bf16_t* __restrict__ vt,
    bf16_t* __restrict__ out)
{
    const int t    = threadIdx.x;
    const int wid  = t >> 6;
    const int lane = t & 63;
    const int quad = lane >> 4;
    const int l15  = lane & 15;

    const int bx = blockIdx.x;                   // 0..1023 (R2/R5 mapping)
    const int u  = bx & 255;
    const int v_ = bx >> 8;                      // 0..3
    const int bh = ((u & 15) << 2) | wid;        // 0..63, XCD-affine
    const int c  = u >> 4;                       // 0..15
    const int bs = (v_ & 1) ? (31 - c) : c;
    const int qt = bs + ((v_ >> 1) << 5);        // per-CU/SIMD sum constant
    const int b  = bh >> 4;
    const int h  = bh & 15;
    const int q0 = qt << 5;

    // bpermute source lanes (byte indices)
    const int s0b = ((((quad << 1)) & 3) * 16 + l15) << 2;
    const int s1b = ((((quad << 1) + 1) & 3) * 16 + l15) << 2;
    const bool lowsel = quad < 2;

    const bf16_t* Qp = qk + (size_t)(b * 2048 + q0 + l15) * 2048 + h * 64 + quad * 8;
    const bf16x8 qa0 = ld8(Qp);
    const bf16x8 qa1 = ld8(Qp + 32);
    const bf16x8 qb0 = ld8(Qp + (size_t)16 * 2048);
    const bf16x8 qb1 = ld8(Qp + (size_t)16 * 2048 + 32);

    const bf16_t* Kbase = qk + (size_t)(b * 2048 + l15) * 2048 + 1024 + h * 64 + quad * 8;
    const bf16_t* Vbase = vt + ((size_t)bh * 64 + l15) * 2048 + quad * 8;

    f32x4 oa[4], ob[4];
#pragma unroll
    for (int v = 0; v < 4; ++v) {
        oa[v] = (f32x4){0.f, 0.f, 0.f, 0.f};
        ob[v] = (f32x4){0.f, 0.f, 0.f, 0.f};
    }
    float la = 0.f, lb = 0.f;

    Kfrag kc = ldk(Kbase, 0);
    Vfrag vc = ldv(Vbase, 0);
    bf16x8 pfa, pfb;

    if (qt > 0) {
        Kfrag kn = ldk(Kbase, 32);               // prefetch K1
        qk_phase<0>(kc, quad, l15, s0b, s1b, lowsel,
                    qa0, qa1, qb0, qb1, pfa, pfb, la, lb);   // P0
        kc = kn;
        for (int kb = 1; kb < qt; ++kb) {
            Kfrag knn = ldk(Kbase, (kb + 1) << 5);   // prefetch K[kb+1]
            Vfrag vn  = ldv(Vbase, kb << 5);         // V[kb], used next iter
            pv(pfa, pfb, vc, oa, ob);                // PV[kb-1] (indep of exp)
            qk_phase<0>(kc, quad, l15, s0b, s1b, lowsel,
                        qa0, qa1, qb0, qb1, pfa, pfb, la, lb);  // P[kb]
            kc = knn; vc = vn;
        }
        Vfrag vn = ldv(Vbase, qt << 5);              // V[qt] (diag)
        pv(pfa, pfb, vc, oa, ob);                    // PV[qt-1]
        qk_phase<1>(kc, quad, l15, s0b, s1b, lowsel,
                    qa0, qa1, qb0, qb1, pfa, pfb, la, lb);      // P[qt] diag
        vc = vn;
    } else {
        qk_phase<1>(kc, quad, l15, s0b, s1b, lowsel,
                    qa0, qa1, qb0, qb1, pfa, pfb, la, lb);
    }
    pv(pfa, pfb, vc, oa, ob);                        // flush diag PV

    // l: sum the 4 quad replicas (lanes i, i+16, i+32, i+48)
    la += __shfl_xor(la, 16); la += __shfl_xor(la, 32);
    lb += __shfl_xor(lb, 16); lb += __shfl_xor(lb, 32);
    const float inva = 1.0f / la;
    const float invb = 1.0f / lb;

    const size_t obase = (size_t)(b * 2048 + q0 + quad * 4) * 1024 + h * 64 + l15;
#pragma unroll
    for (int r = 0; r < 4; ++r) {
        const float ia = __shfl(inva, quad * 4 + r);
        const float ib = __shfl(invb, quad * 4 + r);
#pragma unroll
        for (int v = 0; v < 4; ++v) {
            out[obase + (size_t)r * 1024 + v * 16]        = (bf16_t)(oa[v][r] * ia);
            out[obase + (size_t)(16 + r) * 1024 + v * 16] = (bf16_t)(ob[v][r] * ib);
        }
    }
}

// fp32-visible stamp if the workspace is too small.
__global__ void ws_check_kernel(float* out, int code) {
    if (code != 0 && threadIdx.x == 0) out[0] = (float)code;
}

// ---------------------------------------------------------------------------
extern "C" void kernel_launch(void* const* d_in, const int* in_sizes, int n_in,
                              void* d_out, int out_size, void* d_ws, size_t ws_size,
                              hipStream_t stream)
{
    const void* x    = d_in[0];   // [4,2048,1024]
    const void* wqkv = d_in[1];   // [3072,1024]
    const void* wout = d_in[2];   // [1024,1024]

    // ws: qk 32MB | vt 16MB | attnbuf 16MB = 64MB
    bf16_t* qkbuf   = (bf16_t*)d_ws;
    bf16_t* vtbuf   = qkbuf + (size_t)8192 * 2048;
    bf16_t* attnbuf = vtbuf + (size_t)64 * 64 * 2048;
    float*  outp    = (float*)d_out;

    // scratch aliases (see buffer plan at top)
    bf16_t* xb  = attnbuf;            // 16MB, dead before attn writes attnbuf
    bf16_t* wqb = (bf16_t*)d_out;     // 6MB in d_out, dead before gemm2 writes
    bf16_t* wob = vtbuf;              // 2MB in vt region, converted after attn

    const int wsBad = (ws_size < (size_t)64 * 1024 * 1024) ? 512 : 0;

    // 0) convert x, W_qkv to bf16 (ballot probe: fp32 or bf16 inputs)
    cvt_big_kernel<<<5632, 256, 0, stream>>>(x, wqkv, xb, wqb);

    // 1) QKV projection (bf16 fast path, BK=64): split Q|K + V^T
    gemm_bt_lds<1><<<dim3(24, 64), 256, 0, stream>>>(
        xb, wqb, qkbuf, vtbuf, 8192, 3072, 1024);

    // 2) causal flash attention: 1024 blocks x 4 waves (R5 structure)
    attn_kernel<<<1024, 256, 0, stream>>>(qkbuf, vtbuf, attnbuf);

    // 3) convert W_out (vt region now dead)
    cvt_small_kernel<<<512, 256, 0, stream>>>(wout, wob);

    // 4) output projection (BK=64) -> fp32 d_out (overwrites wqb scratch)
    gemm_bt_lds<0><<<dim3(8, 64), 256, 0, stream>>>(
        attnbuf, wob, outp, nullptr, 8192, 1024, 1024);

    ws_check_kernel<<<1, 64, 0, stream>>>(outp, wsBad);
}